// Round 12
// baseline (77.792 us; speedup 1.0000x reference)
//
#include <hip/hip_runtime.h>
#include <hip/hip_fp16.h>

#define OUT_H 7
#define OUT_W 7
#define NPOS  49
#define RATIO 2
#define SCALE 0.25f
#define CCH 256
#define FH 200
#define FW 200
#define FHW (FH * FW)          // 40000
#define LROW 257               // gather LDS row stride (floats), odd -> conflict-free readout
#define PIXB (CCH * 2)         // 512 B per pixel row in featT

struct __align__(8) H4 { __half2 a, b; };   // 4 fp16 channels

// ---------------- Transpose: (B, 256, 40000) fp32 -> (B, 40000, 256) fp16 ---
// Proven ~15 us (HBM/L3-bound). Do not touch.
__global__ __launch_bounds__(256) void transpose_cp(
    const float* __restrict__ in, __half* __restrict__ outT)
{
    int bid = blockIdx.x;               // grid = B * 4 * 625
    int pt   = bid % 625;               // pixel tile (64 pixels)
    int rest = bid / 625;
    int ct   = rest & 3;                // channel tile (64 ch)
    int b    = rest >> 2;

    __shared__ unsigned short tile[64][66];   // [pix][c]
    int tid = threadIdx.x;
    int pix0 = pt * 64, c0 = ct * 64;
    int xl = tid & 63;

    const float* src = in + ((size_t)b * CCH + c0) * FHW + pix0;
    #pragma unroll
    for (int k = 0; k < 16; ++k) {
        int cl = (tid >> 6) + 4 * k;    // 0..63
        tile[xl][cl] = __half_as_ushort(__float2half(src[(size_t)cl * FHW + xl]));
    }
    __syncthreads();

    __half* dst = outT + ((size_t)b * FHW + pix0) * CCH + c0;
    #pragma unroll
    for (int j = 0; j < 8; ++j) {
        int idx = tid + 256 * j;        // 0..2047
        int pl = idx >> 5;              // 0..63
        int cp = idx & 31;              // half2 index: c = 2*cp
        *(unsigned int*)((char*)dst + (size_t)pl * (CCH * 2) + 4 * cp) =
            *(const unsigned int*)&tile[pl][2 * cp];
    }
}

// ---------------- ROI Align gather v10: wave-coherent corner loads ----------
// One block = one ROI (8 waves, 512 threads, all 256 channels).
// Per (position, corner): the WAVE loads the corner pixel's full 512 B channel
// row -- lane l takes bytes [8l, 8l+8) => ONE contiguous 512 B burst per
// instruction, zero address divergence (vs 16 scattered segments before).
// Lane owns channels 4*lane..4*lane+3 across all 4 corners; weights are
// wave-uniform. Two positions unrolled -> 8 loads in flight.
// Invalid positions (p >= 49) get zero weights and write junk LDS row 49.
__global__ __launch_bounds__(512) void roi_gather_v10(
    const __half* __restrict__ featT,  // (B, 40000, 256) fp16
    const float* __restrict__ rois,    // (N, 5)
    float* __restrict__ out,           // (N, 256, 7, 7)
    int N)
{
    int n   = blockIdx.x;
    int tid = threadIdx.x;
    int wv   = tid >> 6;                // wave 0..7
    int lane = tid & 63;

    __shared__ float lds[50 * LROW];    // row 49 = junk row for invalid p

    const float* r = rois + (size_t)n * 5;
    int   b  = (int)r[0];
    float x1 = r[1] * SCALE, y1 = r[2] * SCALE;
    float roi_w = fmaxf(r[3] * SCALE - x1, 1.0f);
    float roi_h = fmaxf(r[4] * SCALE - y1, 1.0f);
    float step_x = roi_w * (1.0f / (OUT_W * RATIO));
    float step_y = roi_h * (1.0f / (OUT_H * RATIO));

    const char* base = (const char*)featT + (size_t)b * ((size_t)FHW * PIXB);
    const uint32_t loff = (uint32_t)lane * 8;     // lane's 8 B within pixel row

    // Per position: compute 4 corner byte-offsets + wave-uniform weights.
    auto prep = [&](int p, uint32_t (&addr)[4], float (&wt)[4]) {
        int ph = p / OUT_W;
        int pw = p - ph * OUT_W;
        bool pv = (p < NPOS);
        // sample 0 of the 2x2 grid is handled by iy/ix loops below via caller
        // (this lambda is per-sample; see loop)
        (void)pv; (void)ph; (void)pw; (void)addr; (void)wt;
    };
    (void)prep;

    #pragma unroll 1
    for (int ii = 0; ii < 7; ii += 2) {
        int p1 = ii * 8 + wv;           // 0..55
        int p2 = p1 + 8;
        int sp1 = (p1 < NPOS) ? p1 : NPOS;   // junk row 49 if invalid
        int sp2 = (p2 < NPOS) ? p2 : NPOS;

        float acc1[4] = {0.f, 0.f, 0.f, 0.f};
        float acc2[4] = {0.f, 0.f, 0.f, 0.f};

        #pragma unroll
        for (int iy = 0; iy < RATIO; ++iy) {
            #pragma unroll
            for (int ix = 0; ix < RATIO; ++ix) {
                // ---- position 1 sample coords/weights/addrs ----
                uint32_t a1[4]; float w1[4];
                {
                    int ph = p1 / OUT_W, pw = p1 - (p1 / OUT_W) * OUT_W;
                    float yy = y1 + ((float)(ph * RATIO + iy) + 0.5f) * step_y;
                    float xx = x1 + ((float)(pw * RATIO + ix) + 0.5f) * step_x;
                    bool  vv = (p1 < NPOS) && (yy >= -1.0f) && (yy <= (float)FH)
                                          && (xx >= -1.0f) && (xx <= (float)FW);
                    float yc = fminf(fmaxf(yy, 0.0f), (float)(FH - 1));
                    float xc = fminf(fmaxf(xx, 0.0f), (float)(FW - 1));
                    int yi0 = (int)yc, xi0 = (int)xc;
                    float ly = yc - (float)yi0, hy = 1.0f - ly;
                    float lx = xc - (float)xi0, hx = 1.0f - lx;
                    uint32_t rw = (uint32_t)(yi0 * FW + xi0) * PIXB;
                    uint32_t dx = (xi0 < FW - 1) ? PIXB : 0u;
                    uint32_t dy = (yi0 < FH - 1) ? (FW * PIXB) : 0u;
                    a1[0] = rw;        a1[1] = rw + dx;
                    a1[2] = rw + dy;   a1[3] = rw + dy + dx;
                    float vm = vv ? 0.25f : 0.0f;
                    w1[0] = hy * hx * vm; w1[1] = hy * lx * vm;
                    w1[2] = ly * hx * vm; w1[3] = ly * lx * vm;
                }
                // ---- position 2 ----
                uint32_t a2[4]; float w2[4];
                {
                    int ph = p2 / OUT_W, pw = p2 - (p2 / OUT_W) * OUT_W;
                    float yy = y1 + ((float)(ph * RATIO + iy) + 0.5f) * step_y;
                    float xx = x1 + ((float)(pw * RATIO + ix) + 0.5f) * step_x;
                    bool  vv = (p2 < NPOS) && (yy >= -1.0f) && (yy <= (float)FH)
                                          && (xx >= -1.0f) && (xx <= (float)FW);
                    float yc = fminf(fmaxf(yy, 0.0f), (float)(FH - 1));
                    float xc = fminf(fmaxf(xx, 0.0f), (float)(FW - 1));
                    int yi0 = (int)yc, xi0 = (int)xc;
                    float ly = yc - (float)yi0, hy = 1.0f - ly;
                    float lx = xc - (float)xi0, hx = 1.0f - lx;
                    uint32_t rw = (uint32_t)(yi0 * FW + xi0) * PIXB;
                    uint32_t dx = (xi0 < FW - 1) ? PIXB : 0u;
                    uint32_t dy = (yi0 < FH - 1) ? (FW * PIXB) : 0u;
                    a2[0] = rw;        a2[1] = rw + dx;
                    a2[2] = rw + dy;   a2[3] = rw + dy + dx;
                    float vm = vv ? 0.25f : 0.0f;
                    w2[0] = hy * hx * vm; w2[1] = hy * lx * vm;
                    w2[2] = ly * hx * vm; w2[3] = ly * lx * vm;
                }

                // ---- 8 wave-coherent 512 B loads, then FMA ----
                H4 v1[4], v2[4];
                #pragma unroll
                for (int c4 = 0; c4 < 4; ++c4)
                    v1[c4] = *(const H4*)(base + a1[c4] + loff);
                #pragma unroll
                for (int c4 = 0; c4 < 4; ++c4)
                    v2[c4] = *(const H4*)(base + a2[c4] + loff);
                __builtin_amdgcn_sched_barrier(0);

                #pragma unroll
                for (int c4 = 0; c4 < 4; ++c4) {
                    float2 fa = __half22float2(v1[c4].a);
                    float2 fb = __half22float2(v1[c4].b);
                    acc1[0] = fmaf(fa.x, w1[c4], acc1[0]);
                    acc1[1] = fmaf(fa.y, w1[c4], acc1[1]);
                    acc1[2] = fmaf(fb.x, w1[c4], acc1[2]);
                    acc1[3] = fmaf(fb.y, w1[c4], acc1[3]);
                }
                #pragma unroll
                for (int c4 = 0; c4 < 4; ++c4) {
                    float2 fa = __half22float2(v2[c4].a);
                    float2 fb = __half22float2(v2[c4].b);
                    acc2[0] = fmaf(fa.x, w2[c4], acc2[0]);
                    acc2[1] = fmaf(fa.y, w2[c4], acc2[1]);
                    acc2[2] = fmaf(fb.x, w2[c4], acc2[2]);
                    acc2[3] = fmaf(fb.y, w2[c4], acc2[3]);
                }
            }
        }

        // LDS: channel c = 4*lane + k stored at col k*64 + lane.
        // Write banks: (p*257 + k*64 + lane) % 32 = (p + lane) % 32 -> 2/bank.
        #pragma unroll
        for (int k = 0; k < 4; ++k) lds[sp1 * LROW + k * 64 + lane] = acc1[k];
        #pragma unroll
        for (int k = 0; k < 4; ++k) lds[sp2 * LROW + k * 64 + lane] = acc2[k];
    }
    __syncthreads();

    // Readout: contiguous 256*49 floats at out + n*256*49, index = c*49 + p.
    // lds col for channel c: (c&3)*64 + (c>>2). Addr stride LROW (odd) -> free.
    float* oblk = out + (size_t)n * (CCH * NPOS);
    #pragma unroll 1
    for (int o = tid; o < CCH * NPOS; o += 512) {
        int c = o / NPOS;          // magic-mul
        int p = o - c * NPOS;
        __builtin_nontemporal_store(lds[p * LROW + (c & 3) * 64 + (c >> 2)], &oblk[o]);
    }
}

// ---------------- Fallback: direct NCHW (round-1 kernel) --------------------
__global__ __launch_bounds__(256) void roi_align_kernel(
    const float* __restrict__ feat, const float* __restrict__ rois,
    float* __restrict__ out, int N, int C, int H, int W)
{
    int idx = blockIdx.x * blockDim.x + threadIdx.x;
    int total = N * C * OUT_H * OUT_W;
    if (idx >= total) return;
    int pw = idx % OUT_W;
    int ph = (idx / OUT_W) % OUT_H;
    int c  = (idx / (OUT_W * OUT_H)) % C;
    int n  = idx / (OUT_W * OUT_H * C);
    const float* r = rois + (size_t)n * 5;
    int   b  = (int)r[0];
    float x1 = r[1] * SCALE, y1 = r[2] * SCALE;
    float roi_w = fmaxf(r[3] * SCALE - x1, 1.0f);
    float roi_h = fmaxf(r[4] * SCALE - y1, 1.0f);
    float step_y = roi_h * (1.0f / (OUT_H * RATIO));
    float step_x = roi_w * (1.0f / (OUT_W * RATIO));
    const float* fptr = feat + ((size_t)b * C + c) * (size_t)(H * W);
    float acc = 0.0f;
    #pragma unroll
    for (int iy = 0; iy < RATIO; ++iy) {
        float y = y1 + ((float)(ph * RATIO + iy) + 0.5f) * step_y;
        bool vy = (y >= -1.0f) && (y <= (float)H);
        float ycl = fminf(fmaxf(y, 0.0f), (float)(H - 1));
        int y0 = (int)floorf(ycl), y1i = min(y0 + 1, H - 1);
        float ly = ycl - (float)y0, hy = 1.0f - ly;
        #pragma unroll
        for (int ix = 0; ix < RATIO; ++ix) {
            float x = x1 + ((float)(pw * RATIO + ix) + 0.5f) * step_x;
            bool vx = (x >= -1.0f) && (x <= (float)W);
            float xcl = fminf(fmaxf(x, 0.0f), (float)(W - 1));
            int x0 = (int)floorf(xcl), x1i = min(x0 + 1, W - 1);
            float lx = xcl - (float)x0, hx = 1.0f - lx;
            const float* row0 = fptr + (size_t)y0 * W;
            const float* row1 = fptr + (size_t)y1i * W;
            float v = hy * hx * row0[x0] + hy * lx * row0[x1i]
                    + ly * hx * row1[x0] + ly * lx * row1[x1i];
            acc += (vy && vx) ? v : 0.0f;
        }
    }
    out[idx] = acc * (1.0f / (RATIO * RATIO));
}

extern "C" void kernel_launch(void* const* d_in, const int* in_sizes, int n_in,
                              void* d_out, int out_size, void* d_ws, size_t ws_size,
                              hipStream_t stream) {
    const float* feat = (const float*)d_in[0];
    const float* rois = (const float*)d_in[1];
    float* out = (float*)d_out;

    const int N = in_sizes[1] / 5;
    const int B = in_sizes[0] / (CCH * FHW);

    size_t need = (size_t)B * FHW * CCH * sizeof(__half);
    if (ws_size >= need) {
        __half* featT = (__half*)d_ws;
        transpose_cp<<<B * 4 * 625, 256, 0, stream>>>(feat, featT);
        roi_gather_v10<<<N, 512, 0, stream>>>(featT, rois, out, N);
    } else {
        int total = N * CCH * OUT_H * OUT_W;
        roi_align_kernel<<<(total + 255) / 256, 256, 0, stream>>>(
            feat, rois, out, N, CCH, FH, FW);
    }
}